// Round 12
// baseline (199.917 us; speedup 1.0000x reference)
//
#include <hip/hip_runtime.h>
#include <hip/hip_bf16.h>

typedef __attribute__((ext_vector_type(8))) short short8;
typedef __attribute__((ext_vector_type(4))) short short4v;
typedef __attribute__((ext_vector_type(4))) float f32x4;

#define MFMA(A,B,C) __builtin_amdgcn_mfma_f32_16x16x32_bf16(A,B,C,0,0,0)
// swizzle: 3 bits from row bits {0,1,3} so fragment reads spread 8 bank-quads
#define SW(row) ((((row) & 3)) | (((row) >> 1) & 4))
#define SCL 0.18033688f  // 0.125 * log2(e): folded into Q so scores are base-2

__device__ __forceinline__ short f2bs(float f) {
    __hip_bfloat16 h = __float2bfloat16(f);
    union { __hip_bfloat16 h; short s; } u; u.h = h; return u.s;
}

__device__ __forceinline__ float exp2v(float x) {  // bare v_exp_f32 (D = 2^S0)
    float r; asm("v_exp_f32 %0, %1" : "=v"(r) : "v"(x)); return r;
}

__device__ __forceinline__ unsigned cvtpk(float a, float b) {  // bf16(a) | bf16(b)<<16
    unsigned r; asm("v_cvt_pk_bf16_f32 %0, %1, %2" : "=v"(r) : "v"(a), "v"(b)); return r;
}

__device__ __forceinline__ void async16(void* lds, const void* g) {
    __builtin_amdgcn_global_load_lds(
        (const __attribute__((address_space(1))) unsigned int*)g,
        (__attribute__((address_space(3))) unsigned int*)lds, 16, 0, 0);
}

// ---------------- cast fp32 -> bf16, vectorized x4 ----------------
__global__ __launch_bounds__(256) void cast_bf16_k(const float* __restrict__ X,
                                                   short* __restrict__ Y, int n4) {
    int i = blockIdx.x * 256 + threadIdx.x;
    if (i >= n4) return;
    const float4 v = *(const float4*)(X + (size_t)i * 4);
    short4v o;
    o.x = f2bs(v.x); o.y = f2bs(v.y); o.z = f2bs(v.z); o.w = f2bs(v.w);
    *(short4v*)(Y + (size_t)i * 4) = o;
}

// ---------------- transpose + cast: Wt[n][k] = W[k][n] ----------------
__global__ __launch_bounds__(256) void transpose_cast_k(const float* __restrict__ W,
                                                        short* __restrict__ Wt, int K, int N) {
    __shared__ float tile[32][33];
    int n0 = blockIdx.x * 32, k0 = blockIdx.y * 32;
    int tx = threadIdx.x, ty = threadIdx.y;
    #pragma unroll
    for (int i = 0; i < 32; i += 8)
        tile[ty + i][tx] = W[(size_t)(k0 + ty + i) * N + n0 + tx];
    __syncthreads();
    #pragma unroll
    for (int i = 0; i < 32; i += 8)
        Wt[(size_t)(n0 + ty + i) * K + k0 + tx] = f2bs(tile[tx][ty + i]);
}

// ---------------- GEMM 128x256, ring-of-3, counted vmcnt ----------------
// 8 waves (2Mx4N), wave 64x64, 2 phases x 16 MFMA. Distance-2 prefetch: tile
// kt+2's 6 units issued during kt (3/phase); vmcnt(6) at tile end -> kt+1
// landed, kt+2 stays in flight across the barrier (never a hot drain).
// EPI 0: fp32 C row-major (O projection).
// EPI 4: merged QKV: cols [0,2048) Q rope*SCL pack; [2048,2560) K rope pack;
//        [2560,3072) V transposed pack (b,8,64,2048).
template<int EPI>
__global__ __launch_bounds__(512, 2) void gemm128_k(
    const short* __restrict__ A, const short* __restrict__ Bt,
    float* __restrict__ Cf, short* __restrict__ Cq, short* __restrict__ Ck,
    short* __restrict__ Cv,
    const float* __restrict__ rc, const float* __restrict__ rs,
    int M, int N, int K)
{
    extern __shared__ short lds[];   // 3 bufs x (A 128x64 | B 256x64) = 3 x 24576 shorts
    const int t = threadIdx.x;
    const int l = t & 63, w = t >> 6;
    const int lo = l & 15, hi = l >> 4;
    const int wm = w >> 2, wn = w & 3;     // 2M x 4N
    const int lr = l >> 3, ls = l & 7;

    const int nbx = gridDim.x;             // 32
    const int nwg = nbx * gridDim.y;       // multiple of 8
    const int bid0 = blockIdx.y * nbx + blockIdx.x;
    const int wg = (bid0 & 7) * (nwg >> 3) + (bid0 >> 3);
    const int tm = (wg % nbx) * 128, tn = (wg / nbx) * 256;

    const f32x4 z4 = {0.f, 0.f, 0.f, 0.f};
    f32x4 acc[4][4];
    #pragma unroll
    for (int m = 0; m < 4; ++m)
        #pragma unroll
        for (int n = 0; n < 4; ++n) acc[m][n] = z4;

    const int srow = w * 8 + lr;          // 0..63 (row within a 64-row unit)
    const int sswz = ls ^ SW(srow);       // SW depends only on bits 0,1,3

    // unit u: 0-1 = A rows u*64..; 2-5 = B rows (u-2)*64..
    auto stage_unit = [&](int kt, int buf, int u) {
        const size_t ko = (size_t)kt * 64;
        short* base = lds + buf * 24576;
        if (u < 2)
            async16(base + u * 4096 + w * 512,
                    A + (size_t)(tm + u * 64 + srow) * K + ko + sswz * 8);
        else
            async16(base + 8192 + (u - 2) * 4096 + w * 512,
                    Bt + (size_t)(tn + (u - 2) * 64 + srow) * K + ko + sswz * 8);
    };

    const int nkt = K >> 6;   // 32
    #pragma unroll
    for (int u = 0; u < 6; ++u) stage_unit(0, 0, u);
    #pragma unroll
    for (int u = 0; u < 6; ++u) stage_unit(1, 1, u);
    asm volatile("s_waitcnt vmcnt(6)" ::: "memory");   // tile 0 landed
    __builtin_amdgcn_s_barrier();

    int cur = 0;
    for (int kt = 0; kt < nkt; ++kt) {
        int tgt = cur + 2; if (tgt >= 3) tgt -= 3;     // slot of tile kt-1, free
        const bool pf2 = (kt + 2 < nkt);
        const bool pf1 = (kt + 1 < nkt);
        const short* Ab_ = lds + cur * 24576;
        const short* Bb_ = Ab_ + 8192;
        short8 af[4], bfr[4];
        #pragma unroll
        for (int ph = 0; ph < 2; ++ph) {
            const int slot = ph * 4 + hi;
            #pragma unroll
            for (int mm = 0; mm < 4; ++mm) {
                int row = wm * 64 + mm * 16 + lo;
                af[mm] = *(const short8*)(Ab_ + row * 64 + ((slot ^ SW(row)) << 3));
            }
            #pragma unroll
            for (int n = 0; n < 4; ++n) {
                int row = wn * 64 + n * 16 + lo;
                bfr[n] = *(const short8*)(Bb_ + row * 64 + ((slot ^ SW(row)) << 3));
            }
            if (pf2) {
                stage_unit(kt + 2, tgt, ph * 3);
                stage_unit(kt + 2, tgt, ph * 3 + 1);
                stage_unit(kt + 2, tgt, ph * 3 + 2);
            }
            __builtin_amdgcn_s_barrier();
            asm volatile("s_waitcnt lgkmcnt(0)" ::: "memory");
            __builtin_amdgcn_sched_barrier(0);
            __builtin_amdgcn_s_setprio(1);
            #pragma unroll
            for (int n = 0; n < 4; ++n)
                #pragma unroll
                for (int mm = 0; mm < 4; ++mm)
                    acc[mm][n] = MFMA(af[mm], bfr[n], acc[mm][n]);
            __builtin_amdgcn_s_setprio(0);
            if (ph == 1) {
                if (pf2)      asm volatile("s_waitcnt vmcnt(6)" ::: "memory");  // kt+1 landed
                else if (pf1) asm volatile("s_waitcnt vmcnt(0)" ::: "memory");
            }
            __builtin_amdgcn_s_barrier();
        }
        cur = (cur == 2) ? 0 : cur + 1;
    }

    if constexpr (EPI == 0) {
        #pragma unroll
        for (int m = 0; m < 4; ++m)
            #pragma unroll
            for (int r = 0; r < 4; ++r) {
                int row = tm + wm * 64 + m * 16 + hi * 4 + r;
                #pragma unroll
                for (int n = 0; n < 4; ++n) {
                    int col = tn + wn * 64 + n * 16 + lo;
                    Cf[(size_t)row * N + col] = acc[m][n][r];
                }
            }
    } else {
        const int ctn = tn + wn * 64;  // 64-col strip; stays within one region
        if (ctn < 2048) {              // ---- Q: rope + fold softmax scale ----
            #pragma unroll
            for (int m = 0; m < 4; ++m)
                #pragma unroll
                for (int r = 0; r < 4; ++r) {
                    int row = tm + wm * 64 + m * 16 + hi * 4 + r;
                    int b = row >> 11, s = row & 2047;
                    #pragma unroll
                    for (int n = 0; n < 2; ++n) {
                        int col = ctn + n * 16 + lo;
                        int h = col >> 6, d = col & 63;  // d < 32
                        float x1 = acc[m][n][r], x2 = acc[m][n + 2][r];
                        float c = rc[s * 32 + d], sn = rs[s * 32 + d];
                        size_t base = (((size_t)b * 32 + h) * 2048 + s) * 64;
                        Cq[base + d]      = f2bs((x1 * c - x2 * sn) * SCL);
                        Cq[base + d + 32] = f2bs((x1 * sn + x2 * c) * SCL);
                    }
                }
        } else if (ctn < 2560) {       // ---- K: rope pack ----
            #pragma unroll
            for (int m = 0; m < 4; ++m)
                #pragma unroll
                for (int r = 0; r < 4; ++r) {
                    int row = tm + wm * 64 + m * 16 + hi * 4 + r;
                    int b = row >> 11, s = row & 2047;
                    #pragma unroll
                    for (int n = 0; n < 2; ++n) {
                        int col = ctn - 2048 + n * 16 + lo;
                        int h = col >> 6, d = col & 63;  // d < 32
                        float x1 = acc[m][n][r], x2 = acc[m][n + 2][r];
                        float c = rc[s * 32 + d], sn = rs[s * 32 + d];
                        size_t base = (((size_t)b * 8 + h) * 2048 + s) * 64;
                        Ck[base + d]      = f2bs(x1 * c - x2 * sn);
                        Ck[base + d + 32] = f2bs(x1 * sn + x2 * c);
                    }
                }
        } else {                       // ---- V: transposed pack (b,8,64,2048) ----
            #pragma unroll
            for (int m = 0; m < 4; ++m)
                #pragma unroll
                for (int r = 0; r < 4; ++r) {
                    int row = tm + wm * 64 + m * 16 + hi * 4 + r;
                    int b = row >> 11, s = row & 2047;
                    #pragma unroll
                    for (int n = 0; n < 4; ++n) {
                        int col = ctn - 2560 + n * 16 + lo;
                        int h = col >> 6, d = col & 63;
                        Cv[(((size_t)b * 8 + h) * 64 + d) * 2048 + s] = f2bs(acc[m][n][r]);
                    }
                }
        }
    }
}

// ---------------- flash attention, merged dual-qtile, no-max softmax ----------------
// block = (pair 0..15, h, b) owns qtA=pair AND qtB=31-pair in ONE k-loop over
// kt in [0, qtB]: tile B computed every step, tile A only while kt<=qtA. Every
// staged K/V tile and every kf/vf LDS read serves both tiles. Staged tiles
// 33 -> 17..32 (avg 24.5). No-max softmax (scores base-2, |s|<~10).
__global__ __launch_bounds__(256) void attn_k(
    const short* __restrict__ Qp, const short* __restrict__ Kp, const short* __restrict__ Vt,
    short* __restrict__ Ab)
{
    __shared__ short KV[2][8192];  // [buf][ K:0..4095 | V:4096..8191 ], 32 KB
    const int t = threadIdx.x, l = t & 63, w = t >> 6;
    const int lo = l & 15, hi = l >> 4;
    const int lr = l >> 3, ls = l & 7;
    const int pair = blockIdx.x;   // 0..15
    const int h = blockIdx.y, b = blockIdx.z;
    const int kvh = h >> 2;
    const size_t qbase  = (size_t)(b * 32 + h) * 2048 * 64;
    const size_t kbase  = (size_t)(b * 8 + kvh) * 2048 * 64;
    const size_t vtbase = (size_t)(b * 8 + kvh) * 64 * 2048;
    const size_t abase  = (size_t)b * 2048 * 2048 + (size_t)h * 64;

    const int qtA = pair, qtB = 31 - pair;
    const int nkt = qtB + 1;     // 17..32

    short8 qfA[2], qfB[2];
    {
        int qrA = qtA * 64 + w * 16 + lo;
        int qrB = qtB * 64 + w * 16 + lo;
        #pragma unroll
        for (int ks = 0; ks < 2; ++ks) {
            qfA[ks] = *(const short8*)(Qp + qbase + (size_t)qrA * 64 + (ks * 4 + hi) * 8);
            qfB[ks] = *(const short8*)(Qp + qbase + (size_t)qrB * 64 + (ks * 4 + hi) * 8);
        }
    }

    const f32x4 z4 = {0.f, 0.f, 0.f, 0.f};
    float lA = 0.f, lB = 0.f;
    f32x4 oA[4], oB[4];
    #pragma unroll
    for (int nd = 0; nd < 4; ++nd) { oA[nd] = z4; oB[nd] = z4; }

    // softmax+pack for one tile's scores (lane owns q-row = lo, 16 k-slots)
    auto softmax_pack = [&](f32x4 (&s)[4], int qt, int kt, float& lrun, short8 (&afr)[2]) {
        float p[4][4];
        if (kt == qt) {  // diagonal tile: causal mask
            const int q = qt * 64 + w * 16 + lo;
            #pragma unroll
            for (int n = 0; n < 4; ++n)
                #pragma unroll
                for (int r = 0; r < 4; ++r) {
                    int k = kt * 64 + hi * 8 + ((n & 1) << 2) + r + ((n >> 1) << 5);
                    p[n][r] = exp2v((k > q) ? -3e38f : s[n][r]);
                }
        } else {
            #pragma unroll
            for (int n = 0; n < 4; ++n)
                #pragma unroll
                for (int r = 0; r < 4; ++r)
                    p[n][r] = exp2v(s[n][r]);
        }
        float acc = 0.f;
        #pragma unroll
        for (int n = 0; n < 4; ++n)
            #pragma unroll
            for (int r = 0; r < 4; ++r) acc += p[n][r];
        lrun += acc;
        #pragma unroll
        for (int ks = 0; ks < 2; ++ks) {
            union { short8 s8; unsigned u[4]; } pk;
            pk.u[0] = cvtpk(p[2 * ks][0],     p[2 * ks][1]);
            pk.u[1] = cvtpk(p[2 * ks][2],     p[2 * ks][3]);
            pk.u[2] = cvtpk(p[2 * ks + 1][0], p[2 * ks + 1][1]);
            pk.u[3] = cvtpk(p[2 * ks + 1][2], p[2 * ks + 1][3]);
            afr[ks] = pk.s8;
        }
    };

    // prologue: stage kt=0 into buf 0
    #pragma unroll
    for (int j = 0; j < 2; ++j) {
        int g8 = w * 2 + j;
        int row = g8 * 8 + lr;
        int gs = ls ^ SW(row);
        async16(&KV[0][g8 * 512],        Kp + kbase + (size_t)row * 64 + gs * 8);
        async16(&KV[0][4096 + g8 * 512], Vt + vtbase + (size_t)row * 2048 + gs * 8);
    }
    __syncthreads();

    int cur = 0;
    for (int kt = 0; kt < nkt; ++kt) {
        const bool doA = (kt <= qtA);
        if (kt + 1 < nkt) {
            #pragma unroll
            for (int j = 0; j < 2; ++j) {
                int g8 = w * 2 + j;
                int row = g8 * 8 + lr;
                int gs = ls ^ SW(row);
                async16(&KV[cur ^ 1][g8 * 512],
                        Kp + kbase + (size_t)((kt + 1) * 64 + row) * 64 + gs * 8);
                async16(&KV[cur ^ 1][4096 + g8 * 512],
                        Vt + vtbase + (size_t)row * 2048 + (kt + 1) * 64 + gs * 8);
            }
        }

        const short* Ks = &KV[cur][0];
        const short* Vs = &KV[cur][4096];

        // S^T = K Q^T with sigma row permutation; kf shared by both tiles
        f32x4 sA[4], sB[4];
        #pragma unroll
        for (int n = 0; n < 4; ++n) { sA[n] = z4; sB[n] = z4; }
        __builtin_amdgcn_s_setprio(1);
        if (doA) {
            #pragma unroll
            for (int ks = 0; ks < 2; ++ks) {
                const int slot = ks * 4 + hi;
                #pragma unroll
                for (int n = 0; n < 4; ++n) {
                    const int krow = ((lo >> 2) << 3) + ((n & 1) << 2) + (lo & 3) + ((n >> 1) << 5);
                    short8 kf = *(const short8*)(Ks + krow * 64 + ((slot ^ SW(krow)) << 3));
                    sB[n] = MFMA(kf, qfB[ks], sB[n]);
                    sA[n] = MFMA(kf, qfA[ks], sA[n]);
                }
            }
        } else {
            #pragma unroll
            for (int ks = 0; ks < 2; ++ks) {
                const int slot = ks * 4 + hi;
                #pragma unroll
                for (int n = 0; n < 4; ++n) {
                    const int krow = ((lo >> 2) << 3) + ((n & 1) << 2) + (lo & 3) + ((n >> 1) << 5);
                    short8 kf = *(const short8*)(Ks + krow * 64 + ((slot ^ SW(krow)) << 3));
                    sB[n] = MFMA(kf, qfB[ks], sB[n]);
                }
            }
        }
        __builtin_amdgcn_s_setprio(0);

        short8 afrA[2], afrB[2];
        softmax_pack(sB, qtB, kt, lB, afrB);
        if (doA) softmax_pack(sA, qtA, kt, lA, afrA);

        // O += P V ; vf shared by both tiles
        __builtin_amdgcn_s_setprio(1);
        if (doA) {
            #pragma unroll
            for (int ks = 0; ks < 2; ++ks) {
                const int slot = ks * 4 + hi;
                #pragma unroll
                for (int nd = 0; nd < 4; ++nd) {
                    const int vrow = nd * 16 + lo;
                    short8 vf = *(const short8*)(Vs + vrow * 64 + ((slot ^ SW(vrow)) << 3));
                    oB[nd] = MFMA(afrB[ks], vf, oB[nd]);
                    oA[nd] = MFMA(afrA[ks], vf, oA[nd]);
                }
            }
        } else {
            #pragma unroll
            for (int ks = 0; ks < 2; ++ks) {
                const int slot = ks * 4 + hi;
                #pragma unroll
                for (int nd = 0; nd < 4; ++nd) {
                    const int vrow = nd * 16 + lo;
                    short8 vf = *(const short8*)(Vs + vrow * 64 + ((slot ^ SW(vrow)) << 3));
                    oB[nd] = MFMA(afrB[ks], vf, oB[nd]);
                }
            }
        }
        __builtin_amdgcn_s_setprio(0);

        __syncthreads();   // drains prefetch vmcnt + releases buf[cur]
        cur ^= 1;
    }

    // epilogue: per tile, reduce l once, normalize + store
    auto epilogue = [&](int qt, float lrun, f32x4 (&o)[4]) {
        lrun += __shfl_xor(lrun, 16, 64);
        lrun += __shfl_xor(lrun, 32, 64);
        float rl[4];
        #pragma unroll
        for (int r = 0; r < 4; ++r)
            rl[r] = 1.0f / __shfl(lrun, (l & 48) | (hi * 4 + r), 64);
        #pragma unroll
        for (int nd = 0; nd < 4; ++nd)
            #pragma unroll
            for (int r = 0; r < 4; ++r) {
                int s = qt * 64 + w * 16 + hi * 4 + r;
                Ab[abase + (size_t)s * 2048 + nd * 16 + lo] = f2bs(o[nd][r] * rl[r]);
            }
    };
    epilogue(qtB, lB, oB);
    epilogue(qtA, lA, oA);
}

extern "C" void kernel_launch(void* const* d_in, const int* in_sizes, int n_in,
                              void* d_out, int out_size, void* d_ws, size_t ws_size,
                              hipStream_t stream)
{
    const float* x  = (const float*)d_in[0];
    const float* Wq = (const float*)d_in[1];
    const float* Wk = (const float*)d_in[2];
    const float* Wv = (const float*)d_in[3];
    const float* Wo = (const float*)d_in[4];
    const float* rc = (const float*)d_in[5];
    const float* rs = (const float*)d_in[6];
    float* out = (float*)d_out;
    char* ws = (char*)d_ws;

    size_t off = 0;
    short* x_bf   = (short*)(ws + off); off += (size_t)4096 * 2048 * 2;
    short* Wqkv_t = (short*)(ws + off); off += (size_t)3072 * 2048 * 2;
    short* Wo_t   = (short*)(ws + off); off += (size_t)2048 * 2048 * 2;
    short* Qp     = (short*)(ws + off); off += (size_t)2 * 32 * 2048 * 64 * 2;
    short* Kp     = (short*)(ws + off); off += (size_t)2 * 8 * 2048 * 64 * 2;
    short* Vtb    = (short*)(ws + off); off += (size_t)2 * 8 * 64 * 2048 * 2;
    short* Ab     = (short*)(ws + off); off += (size_t)4096 * 2048 * 2;
    if (off > ws_size) return;

    const int LDS_G = 3 * 24576 * 2;   // 144 KB ring-of-3
    (void)hipFuncSetAttribute((const void*)gemm128_k<4>,
                              hipFuncAttributeMaxDynamicSharedMemorySize, LDS_G);
    (void)hipFuncSetAttribute((const void*)gemm128_k<0>,
                              hipFuncAttributeMaxDynamicSharedMemorySize, LDS_G);

    cast_bf16_k<<<8192, 256, 0, stream>>>(x, x_bf, 2097152);
    transpose_cast_k<<<dim3(64, 64), dim3(32, 8), 0, stream>>>(Wq, Wqkv_t, 2048, 2048);
    transpose_cast_k<<<dim3(16, 64), dim3(32, 8), 0, stream>>>(Wk, Wqkv_t + (size_t)2048 * 2048, 2048, 512);
    transpose_cast_k<<<dim3(16, 64), dim3(32, 8), 0, stream>>>(Wv, Wqkv_t + (size_t)2560 * 2048, 2048, 512);
    transpose_cast_k<<<dim3(64, 64), dim3(32, 8), 0, stream>>>(Wo, Wo_t, 2048, 2048);

    // merged QKV projection: 128x256 ring-3 counted-vmcnt, grid (32,12)=384
    gemm128_k<4><<<dim3(32, 12), 512, LDS_G, stream>>>(x_bf, Wqkv_t, nullptr, Qp, Kp, Vtb,
                                                       rc, rs, 4096, 3072, 2048);

    attn_k<<<dim3(16, 32, 2), 256, 0, stream>>>(Qp, Kp, Vtb, Ab);

    // O projection: grid (32,8)=256 blocks (full GPU), ring-3 counted vmcnt
    gemm128_k<0><<<dim3(32, 8), 512, LDS_G, stream>>>(Ab, Wo_t, out, nullptr, nullptr, nullptr,
                                                      nullptr, nullptr, 4096, 2048, 2048);
}

// Round 13
// 183.536 us; speedup vs baseline: 1.0893x; 1.0893x over previous
//
#include <hip/hip_runtime.h>
#include <hip/hip_bf16.h>

typedef __attribute__((ext_vector_type(8))) short short8;
typedef __attribute__((ext_vector_type(4))) short short4v;
typedef __attribute__((ext_vector_type(4))) float f32x4;

#define MFMA(A,B,C) __builtin_amdgcn_mfma_f32_16x16x32_bf16(A,B,C,0,0,0)
// swizzle for BK=64 tiles (bits {0,1,3} of row)
#define SW(row) ((((row) & 3)) | (((row) >> 1) & 4))
// swizzle for BK=32 tiles: slotpos ^= (row&3)^((row>>2)&3) -> <=2-way (free)
#define SW32(row) ((((row) & 3)) ^ (((row) >> 2) & 3))
#define SCL 0.18033688f  // 0.125 * log2(e): folded into Q so scores are base-2

__device__ __forceinline__ short f2bs(float f) {
    __hip_bfloat16 h = __float2bfloat16(f);
    union { __hip_bfloat16 h; short s; } u; u.h = h; return u.s;
}

__device__ __forceinline__ float exp2v(float x) {  // bare v_exp_f32 (D = 2^S0)
    float r; asm("v_exp_f32 %0, %1" : "=v"(r) : "v"(x)); return r;
}

__device__ __forceinline__ unsigned cvtpk(float a, float b) {  // bf16(a) | bf16(b)<<16
    unsigned r; asm("v_cvt_pk_bf16_f32 %0, %1, %2" : "=v"(r) : "v"(a), "v"(b)); return r;
}

__device__ __forceinline__ void async16(void* lds, const void* g) {
    __builtin_amdgcn_global_load_lds(
        (const __attribute__((address_space(1))) unsigned int*)g,
        (__attribute__((address_space(3))) unsigned int*)lds, 16, 0, 0);
}

// ---------------- cast fp32 -> bf16, vectorized x4 ----------------
__global__ __launch_bounds__(256) void cast_bf16_k(const float* __restrict__ X,
                                                   short* __restrict__ Y, int n4) {
    int i = blockIdx.x * 256 + threadIdx.x;
    if (i >= n4) return;
    const float4 v = *(const float4*)(X + (size_t)i * 4);
    short4v o;
    o.x = f2bs(v.x); o.y = f2bs(v.y); o.z = f2bs(v.z); o.w = f2bs(v.w);
    *(short4v*)(Y + (size_t)i * 4) = o;
}

// ---------------- transpose + cast: Wt[n][k] = W[k][n] ----------------
__global__ __launch_bounds__(256) void transpose_cast_k(const float* __restrict__ W,
                                                        short* __restrict__ Wt, int K, int N) {
    __shared__ float tile[32][33];
    int n0 = blockIdx.x * 32, k0 = blockIdx.y * 32;
    int tx = threadIdx.x, ty = threadIdx.y;
    #pragma unroll
    for (int i = 0; i < 32; i += 8)
        tile[ty + i][tx] = W[(size_t)(k0 + ty + i) * N + n0 + tx];
    __syncthreads();
    #pragma unroll
    for (int i = 0; i < 32; i += 8)
        Wt[(size_t)(n0 + ty + i) * K + k0 + tx] = f2bs(tile[tx][ty + i]);
}

// ---------------- QKV GEMM: 128x256 tile, BK=32, ring-of-3 (72 KB) ----------------
// 8 waves (2Mx4N), wave 64x64, 16 MFMA per K-tile, 64 K-tiles. 3 stage units per
// K-tile (A=1, B=2) at distance 2; vmcnt(3) at tile end -> kt+1 landed, kt+2 in
// flight (never a hot drain). 72 KB LDS -> 2 blocks/CU: all 384 blocks resident.
// Epilogue: cols [0,2048) Q rope*SCL pack; [2048,2560) K rope pack;
//           [2560,3072) V transposed pack (b,8,64,2048).
__global__ __launch_bounds__(512, 4) void gemm_qkv_k(
    const short* __restrict__ A, const short* __restrict__ Bt,
    short* __restrict__ Cq, short* __restrict__ Ck, short* __restrict__ Cv,
    const float* __restrict__ rc, const float* __restrict__ rs,
    int M, int N, int K)
{
    extern __shared__ short lds[];   // 3 bufs x (A 128x32 | B 256x32) = 3 x 12288 shorts
    const int t = threadIdx.x;
    const int l = t & 63, w = t >> 6;
    const int lo = l & 15, hi = l >> 4;
    const int wm = w >> 2, wn = w & 3;     // 2M x 4N

    const int nbx = gridDim.x;             // 32
    const int nwg = nbx * gridDim.y;       // 384
    const int bid0 = blockIdx.y * nbx + blockIdx.x;
    const int wg = (bid0 & 7) * (nwg >> 3) + (bid0 >> 3);
    const int tm = (wg % nbx) * 128, tn = (wg / nbx) * 256;

    const f32x4 z4 = {0.f, 0.f, 0.f, 0.f};
    f32x4 acc[4][4];
    #pragma unroll
    for (int m = 0; m < 4; ++m)
        #pragma unroll
        for (int n = 0; n < 4; ++n) acc[m][n] = z4;

    const int srow = t >> 2;               // 0..127 (row within a unit)
    const int scol = (t & 3) ^ SW32(srow); // pre-swizzled source col-group

    // unit 0: A rows 0-127; unit 1: B rows 0-127; unit 2: B rows 128-255
    auto stage_unit = [&](int kt, int buf, int u) {
        const size_t ko = (size_t)kt * 32;
        short* dst = lds + buf * 12288 + u * 4096 + w * 512;  // wave-uniform dest
        if (u == 0)
            async16(dst, A + (size_t)(tm + srow) * K + ko + scol * 8);
        else
            async16(dst, Bt + (size_t)(tn + (u - 1) * 128 + srow) * K + ko + scol * 8);
    };

    const int nkt = K >> 5;   // 64
    #pragma unroll
    for (int u = 0; u < 3; ++u) stage_unit(0, 0, u);
    #pragma unroll
    for (int u = 0; u < 3; ++u) stage_unit(1, 1, u);
    asm volatile("s_waitcnt vmcnt(3)" ::: "memory");   // tile 0 landed
    __builtin_amdgcn_s_barrier();

    int cur = 0;
    for (int kt = 0; kt < nkt; ++kt) {
        int tgt = cur + 2; if (tgt >= 3) tgt -= 3;     // slot of tile kt-1, free
        const bool pf2 = (kt + 2 < nkt);
        const bool pf1 = (kt + 1 < nkt);
        const short* Ab_ = lds + cur * 12288;
        const short* Bb_ = Ab_ + 4096;
        short8 af[4], bfr[4];
        #pragma unroll
        for (int mm = 0; mm < 4; ++mm) {
            int row = wm * 64 + mm * 16 + lo;
            af[mm] = *(const short8*)(Ab_ + row * 32 + ((hi ^ SW32(row)) << 3));
        }
        #pragma unroll
        for (int n = 0; n < 4; ++n) {
            int row = wn * 64 + n * 16 + lo;
            bfr[n] = *(const short8*)(Bb_ + row * 32 + ((hi ^ SW32(row)) << 3));
        }
        if (pf2) {
            stage_unit(kt + 2, tgt, 0);
            stage_unit(kt + 2, tgt, 1);
            stage_unit(kt + 2, tgt, 2);
        }
        __builtin_amdgcn_s_barrier();
        asm volatile("s_waitcnt lgkmcnt(0)" ::: "memory");
        __builtin_amdgcn_sched_barrier(0);
        __builtin_amdgcn_s_setprio(1);
        #pragma unroll
        for (int n = 0; n < 4; ++n)
            #pragma unroll
            for (int mm = 0; mm < 4; ++mm)
                acc[mm][n] = MFMA(af[mm], bfr[n], acc[mm][n]);
        __builtin_amdgcn_s_setprio(0);
        if (pf2)      asm volatile("s_waitcnt vmcnt(3)" ::: "memory");  // kt+1 landed
        else if (pf1) asm volatile("s_waitcnt vmcnt(0)" ::: "memory");
        __builtin_amdgcn_s_barrier();
        cur = (cur == 2) ? 0 : cur + 1;
    }

    const int ctn = tn + wn * 64;  // 64-col strip; stays within one region
    if (ctn < 2048) {              // ---- Q: rope + fold softmax scale ----
        #pragma unroll
        for (int m = 0; m < 4; ++m)
            #pragma unroll
            for (int r = 0; r < 4; ++r) {
                int row = tm + wm * 64 + m * 16 + hi * 4 + r;
                int b = row >> 11, s = row & 2047;
                #pragma unroll
                for (int n = 0; n < 2; ++n) {
                    int col = ctn + n * 16 + lo;
                    int h = col >> 6, d = col & 63;  // d < 32
                    float x1 = acc[m][n][r], x2 = acc[m][n + 2][r];
                    float c = rc[s * 32 + d], sn = rs[s * 32 + d];
                    size_t base = (((size_t)b * 32 + h) * 2048 + s) * 64;
                    Cq[base + d]      = f2bs((x1 * c - x2 * sn) * SCL);
                    Cq[base + d + 32] = f2bs((x1 * sn + x2 * c) * SCL);
                }
            }
    } else if (ctn < 2560) {       // ---- K: rope pack ----
        #pragma unroll
        for (int m = 0; m < 4; ++m)
            #pragma unroll
            for (int r = 0; r < 4; ++r) {
                int row = tm + wm * 64 + m * 16 + hi * 4 + r;
                int b = row >> 11, s = row & 2047;
                #pragma unroll
                for (int n = 0; n < 2; ++n) {
                    int col = ctn - 2048 + n * 16 + lo;
                    int h = col >> 6, d = col & 63;  // d < 32
                    float x1 = acc[m][n][r], x2 = acc[m][n + 2][r];
                    float c = rc[s * 32 + d], sn = rs[s * 32 + d];
                    size_t base = (((size_t)b * 8 + h) * 2048 + s) * 64;
                    Ck[base + d]      = f2bs(x1 * c - x2 * sn);
                    Ck[base + d + 32] = f2bs(x1 * sn + x2 * c);
                }
            }
    } else {                       // ---- V: transposed pack (b,8,64,2048) ----
        #pragma unroll
        for (int m = 0; m < 4; ++m)
            #pragma unroll
            for (int r = 0; r < 4; ++r) {
                int row = tm + wm * 64 + m * 16 + hi * 4 + r;
                int b = row >> 11, s = row & 2047;
                #pragma unroll
                for (int n = 0; n < 4; ++n) {
                    int col = ctn - 2560 + n * 16 + lo;
                    int h = col >> 6, d = col & 63;
                    Cv[(((size_t)b * 8 + h) * 64 + d) * 2048 + s] = f2bs(acc[m][n][r]);
                }
            }
    }
}

// ---------------- O-proj GEMM: 128x256 tile, BK=64, ring-of-3, counted vmcnt ----------------
__global__ __launch_bounds__(512, 2) void gemm_o_k(
    const short* __restrict__ A, const short* __restrict__ Bt,
    float* __restrict__ Cf, int M, int N, int K)
{
    extern __shared__ short lds[];   // 3 bufs x (A 128x64 | B 256x64) = 3 x 24576 shorts
    const int t = threadIdx.x;
    const int l = t & 63, w = t >> 6;
    const int lo = l & 15, hi = l >> 4;
    const int wm = w >> 2, wn = w & 3;     // 2M x 4N
    const int lr = l >> 3, ls = l & 7;

    const int nbx = gridDim.x;             // 32
    const int nwg = nbx * gridDim.y;       // 256
    const int bid0 = blockIdx.y * nbx + blockIdx.x;
    const int wg = (bid0 & 7) * (nwg >> 3) + (bid0 >> 3);
    const int tm = (wg % nbx) * 128, tn = (wg / nbx) * 256;

    const f32x4 z4 = {0.f, 0.f, 0.f, 0.f};
    f32x4 acc[4][4];
    #pragma unroll
    for (int m = 0; m < 4; ++m)
        #pragma unroll
        for (int n = 0; n < 4; ++n) acc[m][n] = z4;

    const int srow = w * 8 + lr;
    const int sswz = ls ^ SW(srow);

    auto stage_unit = [&](int kt, int buf, int u) {
        const size_t ko = (size_t)kt * 64;
        short* base = lds + buf * 24576;
        if (u < 2)
            async16(base + u * 4096 + w * 512,
                    A + (size_t)(tm + u * 64 + srow) * K + ko + sswz * 8);
        else
            async16(base + 8192 + (u - 2) * 4096 + w * 512,
                    Bt + (size_t)(tn + (u - 2) * 64 + srow) * K + ko + sswz * 8);
    };

    const int nkt = K >> 6;   // 32
    #pragma unroll
    for (int u = 0; u < 6; ++u) stage_unit(0, 0, u);
    #pragma unroll
    for (int u = 0; u < 6; ++u) stage_unit(1, 1, u);
    asm volatile("s_waitcnt vmcnt(6)" ::: "memory");
    __builtin_amdgcn_s_barrier();

    int cur = 0;
    for (int kt = 0; kt < nkt; ++kt) {
        int tgt = cur + 2; if (tgt >= 3) tgt -= 3;
        const bool pf2 = (kt + 2 < nkt);
        const bool pf1 = (kt + 1 < nkt);
        const short* Ab_ = lds + cur * 24576;
        const short* Bb_ = Ab_ + 8192;
        short8 af[4], bfr[4];
        #pragma unroll
        for (int ph = 0; ph < 2; ++ph) {
            const int slot = ph * 4 + hi;
            #pragma unroll
            for (int mm = 0; mm < 4; ++mm) {
                int row = wm * 64 + mm * 16 + lo;
                af[mm] = *(const short8*)(Ab_ + row * 64 + ((slot ^ SW(row)) << 3));
            }
            #pragma unroll
            for (int n = 0; n < 4; ++n) {
                int row = wn * 64 + n * 16 + lo;
                bfr[n] = *(const short8*)(Bb_ + row * 64 + ((slot ^ SW(row)) << 3));
            }
            if (pf2) {
                stage_unit(kt + 2, tgt, ph * 3);
                stage_unit(kt + 2, tgt, ph * 3 + 1);
                stage_unit(kt + 2, tgt, ph * 3 + 2);
            }
            __builtin_amdgcn_s_barrier();
            asm volatile("s_waitcnt lgkmcnt(0)" ::: "memory");
            __builtin_amdgcn_sched_barrier(0);
            __builtin_amdgcn_s_setprio(1);
            #pragma unroll
            for (int n = 0; n < 4; ++n)
                #pragma unroll
                for (int mm = 0; mm < 4; ++mm)
                    acc[mm][n] = MFMA(af[mm], bfr[n], acc[mm][n]);
            __builtin_amdgcn_s_setprio(0);
            if (ph == 1) {
                if (pf2)      asm volatile("s_waitcnt vmcnt(6)" ::: "memory");
                else if (pf1) asm volatile("s_waitcnt vmcnt(0)" ::: "memory");
            }
            __builtin_amdgcn_s_barrier();
        }
        cur = (cur == 2) ? 0 : cur + 1;
    }

    #pragma unroll
    for (int m = 0; m < 4; ++m)
        #pragma unroll
        for (int r = 0; r < 4; ++r) {
            int row = tm + wm * 64 + m * 16 + hi * 4 + r;
            #pragma unroll
            for (int n = 0; n < 4; ++n) {
                int col = tn + wn * 64 + n * 16 + lo;
                Cf[(size_t)row * N + col] = acc[m][n][r];
            }
        }
}

// ---------------- flash attention, pair-balanced, no-max softmax ----------------
__global__ __launch_bounds__(256) void attn_k(
    const short* __restrict__ Qp, const short* __restrict__ Kp, const short* __restrict__ Vt,
    short* __restrict__ Ab)
{
    __shared__ short KV[2][8192];  // [buf][ K:0..4095 | V:4096..8191 ], 32 KB
    const int t = threadIdx.x, l = t & 63, w = t >> 6;
    const int lo = l & 15, hi = l >> 4;
    const int lr = l >> 3, ls = l & 7;
    const int pair = blockIdx.x;   // 0..15
    const int h = blockIdx.y, b = blockIdx.z;
    const int kvh = h >> 2;
    const size_t qbase  = (size_t)(b * 32 + h) * 2048 * 64;
    const size_t kbase  = (size_t)(b * 8 + kvh) * 2048 * 64;
    const size_t vtbase = (size_t)(b * 8 + kvh) * 64 * 2048;
    const size_t abase  = (size_t)b * 2048 * 2048 + (size_t)h * 64;

    for (int halfq = 0; halfq < 2; ++halfq) {
        const int qtile = halfq ? 31 - pair : pair;
        const int nkt = qtile + 1;

        short8 qf[2];
        {
            int qrow = qtile * 64 + w * 16 + lo;
            #pragma unroll
            for (int ks = 0; ks < 2; ++ks)
                qf[ks] = *(const short8*)(Qp + qbase + (size_t)qrow * 64 + (ks * 4 + hi) * 8);
        }

        const f32x4 z4 = {0.f, 0.f, 0.f, 0.f};
        float l_run = 0.f;
        f32x4 oacc[4];
        #pragma unroll
        for (int nd = 0; nd < 4; ++nd) oacc[nd] = z4;

        #pragma unroll
        for (int j = 0; j < 2; ++j) {
            int g8 = w * 2 + j;
            int row = g8 * 8 + lr;
            int gs = ls ^ SW(row);
            async16(&KV[0][g8 * 512],        Kp + kbase + (size_t)row * 64 + gs * 8);
            async16(&KV[0][4096 + g8 * 512], Vt + vtbase + (size_t)row * 2048 + gs * 8);
        }
        __syncthreads();

        int cur = 0;
        for (int kt = 0; kt < nkt; ++kt) {
            if (kt + 1 < nkt) {
                #pragma unroll
                for (int j = 0; j < 2; ++j) {
                    int g8 = w * 2 + j;
                    int row = g8 * 8 + lr;
                    int gs = ls ^ SW(row);
                    async16(&KV[cur ^ 1][g8 * 512],
                            Kp + kbase + (size_t)((kt + 1) * 64 + row) * 64 + gs * 8);
                    async16(&KV[cur ^ 1][4096 + g8 * 512],
                            Vt + vtbase + (size_t)row * 2048 + (kt + 1) * 64 + gs * 8);
                }
            }

            const short* Ks = &KV[cur][0];
            const short* Vs = &KV[cur][4096];

            f32x4 sacc[4];
            #pragma unroll
            for (int n = 0; n < 4; ++n) sacc[n] = z4;
            __builtin_amdgcn_s_setprio(1);
            #pragma unroll
            for (int ks = 0; ks < 2; ++ks) {
                const int slot = ks * 4 + hi;
                #pragma unroll
                for (int n = 0; n < 4; ++n) {
                    const int krow = ((lo >> 2) << 3) + ((n & 1) << 2) + (lo & 3) + ((n >> 1) << 5);
                    short8 kf = *(const short8*)(Ks + krow * 64 + ((slot ^ SW(krow)) << 3));
                    sacc[n] = MFMA(kf, qf[ks], sacc[n]);
                }
            }
            __builtin_amdgcn_s_setprio(0);

            float p[4][4];
            if (kt == qtile) {
                const int q = qtile * 64 + w * 16 + lo;
                #pragma unroll
                for (int n = 0; n < 4; ++n)
                    #pragma unroll
                    for (int r = 0; r < 4; ++r) {
                        int k = kt * 64 + hi * 8 + ((n & 1) << 2) + r + ((n >> 1) << 5);
                        p[n][r] = exp2v((k > q) ? -3e38f : sacc[n][r]);
                    }
            } else {
                #pragma unroll
                for (int n = 0; n < 4; ++n)
                    #pragma unroll
                    for (int r = 0; r < 4; ++r)
                        p[n][r] = exp2v(sacc[n][r]);
            }
            float rs0 = 0.f, rs1 = 0.f;
            #pragma unroll
            for (int n = 0; n < 4; ++n) {
                rs0 += p[n][0] + p[n][1];
                rs1 += p[n][2] + p[n][3];
            }
            l_run += rs0 + rs1;

            short8 afr[2];
            #pragma unroll
            for (int ks = 0; ks < 2; ++ks) {
                union { short8 s; unsigned u[4]; } pk;
                pk.u[0] = cvtpk(p[2 * ks][0],     p[2 * ks][1]);
                pk.u[1] = cvtpk(p[2 * ks][2],     p[2 * ks][3]);
                pk.u[2] = cvtpk(p[2 * ks + 1][0], p[2 * ks + 1][1]);
                pk.u[3] = cvtpk(p[2 * ks + 1][2], p[2 * ks + 1][3]);
                afr[ks] = pk.s;
            }

            __builtin_amdgcn_s_setprio(1);
            #pragma unroll
            for (int ks = 0; ks < 2; ++ks) {
                const int slot = ks * 4 + hi;
                #pragma unroll
                for (int nd = 0; nd < 4; ++nd) {
                    const int vrow = nd * 16 + lo;
                    short8 vf = *(const short8*)(Vs + vrow * 64 + ((slot ^ SW(vrow)) << 3));
                    oacc[nd] = MFMA(afr[ks], vf, oacc[nd]);
                }
            }
            __builtin_amdgcn_s_setprio(0);

            __syncthreads();
            cur ^= 1;
        }

        l_run += __shfl_xor(l_run, 16, 64);
        l_run += __shfl_xor(l_run, 32, 64);
        float rl[4];
        #pragma unroll
        for (int r = 0; r < 4; ++r)
            rl[r] = 1.0f / __shfl(l_run, (l & 48) | (hi * 4 + r), 64);
        #pragma unroll
        for (int nd = 0; nd < 4; ++nd)
            #pragma unroll
            for (int r = 0; r < 4; ++r) {
                int s = qtile * 64 + w * 16 + hi * 4 + r;
                Ab[abase + (size_t)s * 2048 + nd * 16 + lo] = f2bs(oacc[nd][r] * rl[r]);
            }
    }
}

extern "C" void kernel_launch(void* const* d_in, const int* in_sizes, int n_in,
                              void* d_out, int out_size, void* d_ws, size_t ws_size,
                              hipStream_t stream)
{
    const float* x  = (const float*)d_in[0];
    const float* Wq = (const float*)d_in[1];
    const float* Wk = (const float*)d_in[2];
    const float* Wv = (const float*)d_in[3];
    const float* Wo = (const float*)d_in[4];
    const float* rc = (const float*)d_in[5];
    const float* rs = (const float*)d_in[6];
    float* out = (float*)d_out;
    char* ws = (char*)d_ws;

    size_t off = 0;
    short* x_bf   = (short*)(ws + off); off += (size_t)4096 * 2048 * 2;
    short* Wqkv_t = (short*)(ws + off); off += (size_t)3072 * 2048 * 2;
    short* Wo_t   = (short*)(ws + off); off += (size_t)2048 * 2048 * 2;
    short* Qp     = (short*)(ws + off); off += (size_t)2 * 32 * 2048 * 64 * 2;
    short* Kp     = (short*)(ws + off); off += (size_t)2 * 8 * 2048 * 64 * 2;
    short* Vtb    = (short*)(ws + off); off += (size_t)2 * 8 * 64 * 2048 * 2;
    short* Ab     = (short*)(ws + off); off += (size_t)4096 * 2048 * 2;
    if (off > ws_size) return;

    const int LDS_QKV = 3 * 12288 * 2;   // 72 KB ring-of-3 (2 blocks/CU)
    const int LDS_O   = 3 * 24576 * 2;   // 144 KB ring-of-3
    (void)hipFuncSetAttribute((const void*)gemm_qkv_k,
                              hipFuncAttributeMaxDynamicSharedMemorySize, LDS_QKV);
    (void)hipFuncSetAttribute((const void*)gemm_o_k,
                              hipFuncAttributeMaxDynamicSharedMemorySize, LDS_O);

    cast_bf16_k<<<8192, 256, 0, stream>>>(x, x_bf, 2097152);
    transpose_cast_k<<<dim3(64, 64), dim3(32, 8), 0, stream>>>(Wq, Wqkv_t, 2048, 2048);
    transpose_cast_k<<<dim3(16, 64), dim3(32, 8), 0, stream>>>(Wk, Wqkv_t + (size_t)2048 * 2048, 2048, 512);
    transpose_cast_k<<<dim3(16, 64), dim3(32, 8), 0, stream>>>(Wv, Wqkv_t + (size_t)2560 * 2048, 2048, 512);
    transpose_cast_k<<<dim3(64, 64), dim3(32, 8), 0, stream>>>(Wo, Wo_t, 2048, 2048);

    // merged QKV projection: 128x256 BK=32 ring-3, grid (32,12)=384, all resident
    gemm_qkv_k<<<dim3(32, 12), 512, LDS_QKV, stream>>>(x_bf, Wqkv_t, Qp, Kp, Vtb,
                                                       rc, rs, 4096, 3072, 2048);

    attn_k<<<dim3(16, 32, 2), 256, 0, stream>>>(Qp, Kp, Vtb, Ab);

    // O projection: grid (32,8)=256 blocks (full GPU), ring-3 counted vmcnt
    gemm_o_k<<<dim3(32, 8), 512, LDS_O, stream>>>(Ab, Wo_t, out, 4096, 2048, 2048);
}

// Round 14
// 181.787 us; speedup vs baseline: 1.0997x; 1.0096x over previous
//
#include <hip/hip_runtime.h>
#include <hip/hip_bf16.h>

typedef __attribute__((ext_vector_type(8))) short short8;
typedef __attribute__((ext_vector_type(4))) short short4v;
typedef __attribute__((ext_vector_type(4))) float f32x4;

#define MFMA(A,B,C) __builtin_amdgcn_mfma_f32_16x16x32_bf16(A,B,C,0,0,0)
// swizzle for BK=64 tiles (bits {0,1,3} of row)
#define SW(row) ((((row) & 3)) | (((row) >> 1) & 4))
// swizzle for BK=32 tiles (slot-group ^= f(row)): even bank-quad spread
#define SW32(row) ((((row) & 3)) ^ (((row) >> 2) & 3))
#define SCL 0.18033688f  // 0.125 * log2(e): folded into Q so scores are base-2

__device__ __forceinline__ short f2bs(float f) {
    __hip_bfloat16 h = __float2bfloat16(f);
    union { __hip_bfloat16 h; short s; } u; u.h = h; return u.s;
}

__device__ __forceinline__ float exp2v(float x) {  // bare v_exp_f32 (D = 2^S0)
    float r; asm("v_exp_f32 %0, %1" : "=v"(r) : "v"(x)); return r;
}

__device__ __forceinline__ unsigned cvtpk(float a, float b) {  // bf16(a) | bf16(b)<<16
    unsigned r; asm("v_cvt_pk_bf16_f32 %0, %1, %2" : "=v"(r) : "v"(a), "v"(b)); return r;
}

__device__ __forceinline__ void async16(void* lds, const void* g) {
    __builtin_amdgcn_global_load_lds(
        (const __attribute__((address_space(1))) unsigned int*)g,
        (__attribute__((address_space(3))) unsigned int*)lds, 16, 0, 0);
}

// ---------------- cast fp32 -> bf16, vectorized x4 ----------------
__global__ __launch_bounds__(256) void cast_bf16_k(const float* __restrict__ X,
                                                   short* __restrict__ Y, int n4) {
    int i = blockIdx.x * 256 + threadIdx.x;
    if (i >= n4) return;
    const float4 v = *(const float4*)(X + (size_t)i * 4);
    short4v o;
    o.x = f2bs(v.x); o.y = f2bs(v.y); o.z = f2bs(v.z); o.w = f2bs(v.w);
    *(short4v*)(Y + (size_t)i * 4) = o;
}

// ---------------- transpose + cast: Wt[n][k] = W[k][n] ----------------
__global__ __launch_bounds__(256) void transpose_cast_k(const float* __restrict__ W,
                                                        short* __restrict__ Wt, int K, int N) {
    __shared__ float tile[32][33];
    int n0 = blockIdx.x * 32, k0 = blockIdx.y * 32;
    int tx = threadIdx.x, ty = threadIdx.y;
    #pragma unroll
    for (int i = 0; i < 32; i += 8)
        tile[ty + i][tx] = W[(size_t)(k0 + ty + i) * N + n0 + tx];
    __syncthreads();
    #pragma unroll
    for (int i = 0; i < 32; i += 8)
        Wt[(size_t)(n0 + ty + i) * K + k0 + tx] = f2bs(tile[tx][ty + i]);
}

// ---------------- QKV GEMM: 128x128 tile, BK=32, ring-of-3 (48 KB) ----------------
// 4 waves (2Mx2N), wave 64x64, 16 MFMA per K-tile (single ks: slot=hi), 64 K-tiles.
// 4 stage units/K-tile (A lo/hi, B lo/hi) at distance 2; vmcnt(4) at tile end ->
// kt+1 landed, kt+2 in flight (never hot). 48 KB -> 3 blocks/CU: grid 768 = 3x256
// ALL co-resident (zero tail, zero fill quantization), 3 waves/SIMD TLP.
// Epilogue: cols [0,2048) Q rope*SCL pack; [2048,2560) K rope pack;
//           [2560,3072) V transposed pack (b,8,64,2048).
__global__ __launch_bounds__(256, 3) void gemm_qkv_k(
    const short* __restrict__ A, const short* __restrict__ Bt,
    short* __restrict__ Cq, short* __restrict__ Ck, short* __restrict__ Cv,
    const float* __restrict__ rc, const float* __restrict__ rs,
    int M, int N, int K)
{
    extern __shared__ short lds[];   // 3 bufs x (A 128x32 | B 128x32) = 3 x 8192 shorts
    const int t = threadIdx.x;       // 256
    const int l = t & 63, w = t >> 6;    // 4 waves
    const int lo = l & 15, hi = l >> 4;
    const int wm = w >> 1, wn = w & 1;   // 2M x 2N

    const int nbx = gridDim.x;           // 32
    const int nwg = nbx * gridDim.y;     // 768
    const int bid0 = blockIdx.y * nbx + blockIdx.x;
    const int wg = (bid0 & 7) * (nwg >> 3) + (bid0 >> 3);
    const int tm = (wg % nbx) * 128, tn = (wg / nbx) * 128;

    const f32x4 z4 = {0.f, 0.f, 0.f, 0.f};
    f32x4 acc[4][4];
    #pragma unroll
    for (int m = 0; m < 4; ++m)
        #pragma unroll
        for (int n = 0; n < 4; ++n) acc[m][n] = z4;

    const int srow = t >> 2;                  // 0..63 (row within a 64-row unit)
    const int scol = (t & 3) ^ SW32(srow);    // SW32 ignores bit 6, so unit-safe

    // unit u: 0/1 = A rows 0-63/64-127; 2/3 = B rows 0-63/64-127
    auto stage_unit = [&](int kt, int buf, int u) {
        short* dst = lds + buf * 8192 + (u >> 1) * 4096 + (u & 1) * 2048 + w * 512;
        const short* src = (u < 2)
            ? A  + (size_t)(tm + (u & 1) * 64 + srow) * K + kt * 32 + scol * 8
            : Bt + (size_t)(tn + (u & 1) * 64 + srow) * K + kt * 32 + scol * 8;
        async16(dst, src);
    };

    const int nkt = K >> 5;   // 64
    #pragma unroll
    for (int u = 0; u < 4; ++u) stage_unit(0, 0, u);
    #pragma unroll
    for (int u = 0; u < 4; ++u) stage_unit(1, 1, u);
    asm volatile("s_waitcnt vmcnt(4)" ::: "memory");   // tile 0 landed
    __builtin_amdgcn_s_barrier();

    int cur = 0;
    for (int kt = 0; kt < nkt; ++kt) {
        int tgt = cur + 2; if (tgt >= 3) tgt -= 3;     // slot of tile kt-1, free
        const bool pf2 = (kt + 2 < nkt);
        const bool pf1 = (kt + 1 < nkt);
        const short* Ab_ = lds + cur * 8192;
        const short* Bb_ = Ab_ + 4096;
        short8 af[4], bfr[4];
        #pragma unroll
        for (int mm = 0; mm < 4; ++mm) {
            int row = wm * 64 + mm * 16 + lo;
            af[mm] = *(const short8*)(Ab_ + row * 32 + ((hi ^ SW32(row)) << 3));
        }
        #pragma unroll
        for (int n = 0; n < 4; ++n) {
            int row = wn * 64 + n * 16 + lo;
            bfr[n] = *(const short8*)(Bb_ + row * 32 + ((hi ^ SW32(row)) << 3));
        }
        if (pf2) {
            #pragma unroll
            for (int u = 0; u < 4; ++u) stage_unit(kt + 2, tgt, u);
        }
        __builtin_amdgcn_s_barrier();
        asm volatile("s_waitcnt lgkmcnt(0)" ::: "memory");
        __builtin_amdgcn_sched_barrier(0);
        __builtin_amdgcn_s_setprio(1);
        #pragma unroll
        for (int n = 0; n < 4; ++n)
            #pragma unroll
            for (int mm = 0; mm < 4; ++mm)
                acc[mm][n] = MFMA(af[mm], bfr[n], acc[mm][n]);
        __builtin_amdgcn_s_setprio(0);
        if (pf2)      asm volatile("s_waitcnt vmcnt(4)" ::: "memory");  // kt+1 landed
        else if (pf1) asm volatile("s_waitcnt vmcnt(0)" ::: "memory");
        __builtin_amdgcn_s_barrier();
        cur = (cur == 2) ? 0 : cur + 1;
    }

    const int ctn = tn + wn * 64;  // 64-col strip; stays within one region
    if (ctn < 2048) {              // ---- Q: rope + fold softmax scale ----
        #pragma unroll
        for (int m = 0; m < 4; ++m)
            #pragma unroll
            for (int r = 0; r < 4; ++r) {
                int row = tm + wm * 64 + m * 16 + hi * 4 + r;
                int b = row >> 11, s = row & 2047;
                #pragma unroll
                for (int n = 0; n < 2; ++n) {
                    int col = ctn + n * 16 + lo;
                    int h = col >> 6, d = col & 63;  // d < 32
                    float x1 = acc[m][n][r], x2 = acc[m][n + 2][r];
                    float c = rc[s * 32 + d], sn = rs[s * 32 + d];
                    size_t base = (((size_t)b * 32 + h) * 2048 + s) * 64;
                    Cq[base + d]      = f2bs((x1 * c - x2 * sn) * SCL);
                    Cq[base + d + 32] = f2bs((x1 * sn + x2 * c) * SCL);
                }
            }
    } else if (ctn < 2560) {       // ---- K: rope pack ----
        #pragma unroll
        for (int m = 0; m < 4; ++m)
            #pragma unroll
            for (int r = 0; r < 4; ++r) {
                int row = tm + wm * 64 + m * 16 + hi * 4 + r;
                int b = row >> 11, s = row & 2047;
                #pragma unroll
                for (int n = 0; n < 2; ++n) {
                    int col = ctn - 2048 + n * 16 + lo;
                    int h = col >> 6, d = col & 63;  // d < 32
                    float x1 = acc[m][n][r], x2 = acc[m][n + 2][r];
                    float c = rc[s * 32 + d], sn = rs[s * 32 + d];
                    size_t base = (((size_t)b * 8 + h) * 2048 + s) * 64;
                    Ck[base + d]      = f2bs(x1 * c - x2 * sn);
                    Ck[base + d + 32] = f2bs(x1 * sn + x2 * c);
                }
            }
    } else {                       // ---- V: transposed pack (b,8,64,2048) ----
        #pragma unroll
        for (int m = 0; m < 4; ++m)
            #pragma unroll
            for (int r = 0; r < 4; ++r) {
                int row = tm + wm * 64 + m * 16 + hi * 4 + r;
                int b = row >> 11, s = row & 2047;
                #pragma unroll
                for (int n = 0; n < 4; ++n) {
                    int col = ctn - 2560 + n * 16 + lo;
                    int h = col >> 6, d = col & 63;
                    Cv[(((size_t)b * 8 + h) * 64 + d) * 2048 + s] = f2bs(acc[m][n][r]);
                }
            }
    }
}

// ---------------- O-proj GEMM: 128x256 tile, BK=64, ring-of-3, counted vmcnt ----------------
__global__ __launch_bounds__(512, 2) void gemm_o_k(
    const short* __restrict__ A, const short* __restrict__ Bt,
    float* __restrict__ Cf, int M, int N, int K)
{
    extern __shared__ short lds[];   // 3 bufs x (A 128x64 | B 256x64) = 3 x 24576 shorts
    const int t = threadIdx.x;
    const int l = t & 63, w = t >> 6;
    const int lo = l & 15, hi = l >> 4;
    const int wm = w >> 2, wn = w & 3;     // 2M x 4N
    const int lr = l >> 3, ls = l & 7;

    const int nbx = gridDim.x;             // 32
    const int nwg = nbx * gridDim.y;       // 256
    const int bid0 = blockIdx.y * nbx + blockIdx.x;
    const int wg = (bid0 & 7) * (nwg >> 3) + (bid0 >> 3);
    const int tm = (wg % nbx) * 128, tn = (wg / nbx) * 256;

    const f32x4 z4 = {0.f, 0.f, 0.f, 0.f};
    f32x4 acc[4][4];
    #pragma unroll
    for (int m = 0; m < 4; ++m)
        #pragma unroll
        for (int n = 0; n < 4; ++n) acc[m][n] = z4;

    const int srow = w * 8 + lr;
    const int sswz = ls ^ SW(srow);

    auto stage_unit = [&](int kt, int buf, int u) {
        const size_t ko = (size_t)kt * 64;
        short* base = lds + buf * 24576;
        if (u < 2)
            async16(base + u * 4096 + w * 512,
                    A + (size_t)(tm + u * 64 + srow) * K + ko + sswz * 8);
        else
            async16(base + 8192 + (u - 2) * 4096 + w * 512,
                    Bt + (size_t)(tn + (u - 2) * 64 + srow) * K + ko + sswz * 8);
    };

    const int nkt = K >> 6;   // 32
    #pragma unroll
    for (int u = 0; u < 6; ++u) stage_unit(0, 0, u);
    #pragma unroll
    for (int u = 0; u < 6; ++u) stage_unit(1, 1, u);
    asm volatile("s_waitcnt vmcnt(6)" ::: "memory");
    __builtin_amdgcn_s_barrier();

    int cur = 0;
    for (int kt = 0; kt < nkt; ++kt) {
        int tgt = cur + 2; if (tgt >= 3) tgt -= 3;
        const bool pf2 = (kt + 2 < nkt);
        const bool pf1 = (kt + 1 < nkt);
        const short* Ab_ = lds + cur * 24576;
        const short* Bb_ = Ab_ + 8192;
        short8 af[4], bfr[4];
        #pragma unroll
        for (int ph = 0; ph < 2; ++ph) {
            const int slot = ph * 4 + hi;
            #pragma unroll
            for (int mm = 0; mm < 4; ++mm) {
                int row = wm * 64 + mm * 16 + lo;
                af[mm] = *(const short8*)(Ab_ + row * 64 + ((slot ^ SW(row)) << 3));
            }
            #pragma unroll
            for (int n = 0; n < 4; ++n) {
                int row = wn * 64 + n * 16 + lo;
                bfr[n] = *(const short8*)(Bb_ + row * 64 + ((slot ^ SW(row)) << 3));
            }
            if (pf2) {
                stage_unit(kt + 2, tgt, ph * 3);
                stage_unit(kt + 2, tgt, ph * 3 + 1);
                stage_unit(kt + 2, tgt, ph * 3 + 2);
            }
            __builtin_amdgcn_s_barrier();
            asm volatile("s_waitcnt lgkmcnt(0)" ::: "memory");
            __builtin_amdgcn_sched_barrier(0);
            __builtin_amdgcn_s_setprio(1);
            #pragma unroll
            for (int n = 0; n < 4; ++n)
                #pragma unroll
                for (int mm = 0; mm < 4; ++mm)
                    acc[mm][n] = MFMA(af[mm], bfr[n], acc[mm][n]);
            __builtin_amdgcn_s_setprio(0);
            if (ph == 1) {
                if (pf2)      asm volatile("s_waitcnt vmcnt(6)" ::: "memory");
                else if (pf1) asm volatile("s_waitcnt vmcnt(0)" ::: "memory");
            }
            __builtin_amdgcn_s_barrier();
        }
        cur = (cur == 2) ? 0 : cur + 1;
    }

    #pragma unroll
    for (int m = 0; m < 4; ++m)
        #pragma unroll
        for (int r = 0; r < 4; ++r) {
            int row = tm + wm * 64 + m * 16 + hi * 4 + r;
            #pragma unroll
            for (int n = 0; n < 4; ++n) {
                int col = tn + wn * 64 + n * 16 + lo;
                Cf[(size_t)row * N + col] = acc[m][n][r];
            }
        }
}

// ---------------- flash attention, pair-balanced, no-max softmax ----------------
__global__ __launch_bounds__(256) void attn_k(
    const short* __restrict__ Qp, const short* __restrict__ Kp, const short* __restrict__ Vt,
    short* __restrict__ Ab)
{
    __shared__ short KV[2][8192];  // [buf][ K:0..4095 | V:4096..8191 ], 32 KB
    const int t = threadIdx.x, l = t & 63, w = t >> 6;
    const int lo = l & 15, hi = l >> 4;
    const int lr = l >> 3, ls = l & 7;
    const int pair = blockIdx.x;   // 0..15
    const int h = blockIdx.y, b = blockIdx.z;
    const int kvh = h >> 2;
    const size_t qbase  = (size_t)(b * 32 + h) * 2048 * 64;
    const size_t kbase  = (size_t)(b * 8 + kvh) * 2048 * 64;
    const size_t vtbase = (size_t)(b * 8 + kvh) * 64 * 2048;
    const size_t abase  = (size_t)b * 2048 * 2048 + (size_t)h * 64;

    for (int halfq = 0; halfq < 2; ++halfq) {
        const int qtile = halfq ? 31 - pair : pair;
        const int nkt = qtile + 1;

        short8 qf[2];
        {
            int qrow = qtile * 64 + w * 16 + lo;
            #pragma unroll
            for (int ks = 0; ks < 2; ++ks)
                qf[ks] = *(const short8*)(Qp + qbase + (size_t)qrow * 64 + (ks * 4 + hi) * 8);
        }

        const f32x4 z4 = {0.f, 0.f, 0.f, 0.f};
        float l_run = 0.f;
        f32x4 oacc[4];
        #pragma unroll
        for (int nd = 0; nd < 4; ++nd) oacc[nd] = z4;

        #pragma unroll
        for (int j = 0; j < 2; ++j) {
            int g8 = w * 2 + j;
            int row = g8 * 8 + lr;
            int gs = ls ^ SW(row);
            async16(&KV[0][g8 * 512],        Kp + kbase + (size_t)row * 64 + gs * 8);
            async16(&KV[0][4096 + g8 * 512], Vt + vtbase + (size_t)row * 2048 + gs * 8);
        }
        __syncthreads();

        int cur = 0;
        for (int kt = 0; kt < nkt; ++kt) {
            if (kt + 1 < nkt) {
                #pragma unroll
                for (int j = 0; j < 2; ++j) {
                    int g8 = w * 2 + j;
                    int row = g8 * 8 + lr;
                    int gs = ls ^ SW(row);
                    async16(&KV[cur ^ 1][g8 * 512],
                            Kp + kbase + (size_t)((kt + 1) * 64 + row) * 64 + gs * 8);
                    async16(&KV[cur ^ 1][4096 + g8 * 512],
                            Vt + vtbase + (size_t)row * 2048 + (kt + 1) * 64 + gs * 8);
                }
            }

            const short* Ks = &KV[cur][0];
            const short* Vs = &KV[cur][4096];

            f32x4 sacc[4];
            #pragma unroll
            for (int n = 0; n < 4; ++n) sacc[n] = z4;
            __builtin_amdgcn_s_setprio(1);
            #pragma unroll
            for (int ks = 0; ks < 2; ++ks) {
                const int slot = ks * 4 + hi;
                #pragma unroll
                for (int n = 0; n < 4; ++n) {
                    const int krow = ((lo >> 2) << 3) + ((n & 1) << 2) + (lo & 3) + ((n >> 1) << 5);
                    short8 kf = *(const short8*)(Ks + krow * 64 + ((slot ^ SW(krow)) << 3));
                    sacc[n] = MFMA(kf, qf[ks], sacc[n]);
                }
            }
            __builtin_amdgcn_s_setprio(0);

            float p[4][4];
            if (kt == qtile) {
                const int q = qtile * 64 + w * 16 + lo;
                #pragma unroll
                for (int n = 0; n < 4; ++n)
                    #pragma unroll
                    for (int r = 0; r < 4; ++r) {
                        int k = kt * 64 + hi * 8 + ((n & 1) << 2) + r + ((n >> 1) << 5);
                        p[n][r] = exp2v((k > q) ? -3e38f : sacc[n][r]);
                    }
            } else {
                #pragma unroll
                for (int n = 0; n < 4; ++n)
                    #pragma unroll
                    for (int r = 0; r < 4; ++r)
                        p[n][r] = exp2v(sacc[n][r]);
            }
            float rs0 = 0.f, rs1 = 0.f;
            #pragma unroll
            for (int n = 0; n < 4; ++n) {
                rs0 += p[n][0] + p[n][1];
                rs1 += p[n][2] + p[n][3];
            }
            l_run += rs0 + rs1;

            short8 afr[2];
            #pragma unroll
            for (int ks = 0; ks < 2; ++ks) {
                union { short8 s; unsigned u[4]; } pk;
                pk.u[0] = cvtpk(p[2 * ks][0],     p[2 * ks][1]);
                pk.u[1] = cvtpk(p[2 * ks][2],     p[2 * ks][3]);
                pk.u[2] = cvtpk(p[2 * ks + 1][0], p[2 * ks + 1][1]);
                pk.u[3] = cvtpk(p[2 * ks + 1][2], p[2 * ks + 1][3]);
                afr[ks] = pk.s;
            }

            __builtin_amdgcn_s_setprio(1);
            #pragma unroll
            for (int ks = 0; ks < 2; ++ks) {
                const int slot = ks * 4 + hi;
                #pragma unroll
                for (int nd = 0; nd < 4; ++nd) {
                    const int vrow = nd * 16 + lo;
                    short8 vf = *(const short8*)(Vs + vrow * 64 + ((slot ^ SW(vrow)) << 3));
                    oacc[nd] = MFMA(afr[ks], vf, oacc[nd]);
                }
            }
            __builtin_amdgcn_s_setprio(0);

            __syncthreads();
            cur ^= 1;
        }

        l_run += __shfl_xor(l_run, 16, 64);
        l_run += __shfl_xor(l_run, 32, 64);
        float rl[4];
        #pragma unroll
        for (int r = 0; r < 4; ++r)
            rl[r] = 1.0f / __shfl(l_run, (l & 48) | (hi * 4 + r), 64);
        #pragma unroll
        for (int nd = 0; nd < 4; ++nd)
            #pragma unroll
            for (int r = 0; r < 4; ++r) {
                int s = qtile * 64 + w * 16 + hi * 4 + r;
                Ab[abase + (size_t)s * 2048 + nd * 16 + lo] = f2bs(oacc[nd][r] * rl[r]);
            }
    }
}

extern "C" void kernel_launch(void* const* d_in, const int* in_sizes, int n_in,
                              void* d_out, int out_size, void* d_ws, size_t ws_size,
                              hipStream_t stream)
{
    const float* x  = (const float*)d_in[0];
    const float* Wq = (const float*)d_in[1];
    const float* Wk = (const float*)d_in[2];
    const float* Wv = (const float*)d_in[3];
    const float* Wo = (const float*)d_in[4];
    const float* rc = (const float*)d_in[5];
    const float* rs = (const float*)d_in[6];
    float* out = (float*)d_out;
    char* ws = (char*)d_ws;

    size_t off = 0;
    short* x_bf   = (short*)(ws + off); off += (size_t)4096 * 2048 * 2;
    short* Wqkv_t = (short*)(ws + off); off += (size_t)3072 * 2048 * 2;
    short* Wo_t   = (short*)(ws + off); off += (size_t)2048 * 2048 * 2;
    short* Qp     = (short*)(ws + off); off += (size_t)2 * 32 * 2048 * 64 * 2;
    short* Kp     = (short*)(ws + off); off += (size_t)2 * 8 * 2048 * 64 * 2;
    short* Vtb    = (short*)(ws + off); off += (size_t)2 * 8 * 64 * 2048 * 2;
    short* Ab     = (short*)(ws + off); off += (size_t)4096 * 2048 * 2;
    if (off > ws_size) return;

    const int LDS_QKV = 3 * 8192 * 2;    // 48 KB ring-of-3 (3 blocks/CU)
    const int LDS_O   = 3 * 24576 * 2;   // 144 KB ring-of-3
    (void)hipFuncSetAttribute((const void*)gemm_qkv_k,
                              hipFuncAttributeMaxDynamicSharedMemorySize, LDS_QKV);
    (void)hipFuncSetAttribute((const void*)gemm_o_k,
                              hipFuncAttributeMaxDynamicSharedMemorySize, LDS_O);

    cast_bf16_k<<<8192, 256, 0, stream>>>(x, x_bf, 2097152);
    transpose_cast_k<<<dim3(64, 64), dim3(32, 8), 0, stream>>>(Wq, Wqkv_t, 2048, 2048);
    transpose_cast_k<<<dim3(16, 64), dim3(32, 8), 0, stream>>>(Wk, Wqkv_t + (size_t)2048 * 2048, 2048, 512);
    transpose_cast_k<<<dim3(16, 64), dim3(32, 8), 0, stream>>>(Wv, Wqkv_t + (size_t)2560 * 2048, 2048, 512);
    transpose_cast_k<<<dim3(64, 64), dim3(32, 8), 0, stream>>>(Wo, Wo_t, 2048, 2048);

    // merged QKV projection: 128x128 BK=32 ring-3, grid (32,24)=768 = 3x256 all-resident
    gemm_qkv_k<<<dim3(32, 24), 256, LDS_QKV, stream>>>(x_bf, Wqkv_t, Qp, Kp, Vtb,
                                                       rc, rs, 4096, 3072, 2048);

    attn_k<<<dim3(16, 32, 2), 256, 0, stream>>>(Qp, Kp, Vtb, Ab);

    // O projection: grid (32,8)=256 blocks (full GPU), ring-3 counted vmcnt
    gemm_o_k<<<dim3(32, 8), 512, LDS_O, stream>>>(Ab, Wo_t, out, 4096, 2048, 2048);
}